// Round 1
// baseline (749.127 us; speedup 1.0000x reference)
//
#include <hip/hip_runtime.h>
#include <math.h>

// Problem constants (match reference)
#define INVALID_TOKEN_ID (-1)
constexpr int BB = 128;          // batch
constexpr int KK = 8;            // spec length
constexpr int VV = 128000;       // vocab
constexpr int ROWS = BB * (KK + 1);   // 1152 rows of target_probs
constexpr int THREADS = 256;

// Kernel 1: per-row argmax over V=128000 fp32, first-occurrence tie-break
// (matches jnp.argmax). One block per row; float4 coalesced loads.
__global__ __launch_bounds__(THREADS) void argmax_rows_kernel(
    const float* __restrict__ probs, int* __restrict__ amax_out) {
    const int row = blockIdx.x;
    const int tid = threadIdx.x;
    const float4* __restrict__ p4 =
        (const float4*)(probs + (size_t)row * VV);

    float best = -INFINITY;
    int bestIdx = VV;  // sentinel (larger than any real index)

    // V/4 = 32000 float4s; 32000 % 256 == 0 -> exactly 125 iters/thread.
    // Within a thread indices are strictly increasing, so strict '>'
    // preserves first-occurrence semantics.
    #pragma unroll 5
    for (int i = tid; i < VV / 4; i += THREADS) {
        float4 v = p4[i];
        int base = i * 4;
        if (v.x > best) { best = v.x; bestIdx = base; }
        if (v.y > best) { best = v.y; bestIdx = base + 1; }
        if (v.z > best) { best = v.z; bestIdx = base + 2; }
        if (v.w > best) { best = v.w; bestIdx = base + 3; }
    }

    // Wave (64-lane) reduction, lexicographic (value desc, index asc).
    #pragma unroll
    for (int off = 32; off > 0; off >>= 1) {
        float ov = __shfl_down(best, off, 64);
        int   oi = __shfl_down(bestIdx, off, 64);
        if (ov > best || (ov == best && oi < bestIdx)) {
            best = ov;
            bestIdx = oi;
        }
    }

    // Cross-wave reduction via LDS (4 waves per block).
    __shared__ float s_v[THREADS / 64];
    __shared__ int   s_i[THREADS / 64];
    const int wave = tid >> 6;
    const int lane = tid & 63;
    if (lane == 0) {
        s_v[wave] = best;
        s_i[wave] = bestIdx;
    }
    __syncthreads();
    if (tid == 0) {
        #pragma unroll
        for (int w = 1; w < THREADS / 64; ++w) {
            if (s_v[w] > best || (s_v[w] == best && s_i[w] < bestIdx)) {
                best = s_v[w];
                bestIdx = s_i[w];
            }
        }
        amax_out[row] = bestIdx;
    }
}

// Kernel 2: accept-mask logic. One thread per batch row.
// r = length of accepted draft prefix; emit argmax token for j <= r
// (position r is the bonus/corrected token), else INVALID_TOKEN_ID.
__global__ __launch_bounds__(128) void finalize_kernel(
    const int* __restrict__ draft, const int* __restrict__ amax,
    int* __restrict__ out) {
    const int b = threadIdx.x;
    if (b >= BB) return;
    const int* arow = amax + b * (KK + 1);
    const int* drow = draft + b * KK;
    int r = 0;
    while (r < KK && arow[r] == drow[r]) ++r;
    int* orow = out + b * (KK + 1);
    #pragma unroll
    for (int j = 0; j <= KK; ++j) {
        orow[j] = (j <= r) ? arow[j] : INVALID_TOKEN_ID;
    }
}

extern "C" void kernel_launch(void* const* d_in, const int* in_sizes, int n_in,
                              void* d_out, int out_size, void* d_ws, size_t ws_size,
                              hipStream_t stream) {
    const int*   draft = (const int*)d_in[0];     // [B, K] int32
    const float* probs = (const float*)d_in[1];   // [B*(K+1), V] fp32
    int* out  = (int*)d_out;                      // [B, K+1] int32
    int* amax = (int*)d_ws;                       // 1152 ints of scratch

    argmax_rows_kernel<<<ROWS, THREADS, 0, stream>>>(probs, amax);
    finalize_kernel<<<1, 128, 0, stream>>>(draft, amax, out);
}